// Round 8
// baseline (130.687 us; speedup 1.0000x reference)
//
#include <hip/hip_runtime.h>
#include <hip/hip_bf16.h>

#define NN 10000
#define NE 320000
#define IN_DIM 256
#define HID_DIM 512
#define OUT_DIM 256
#define CAP 96   // per-node edge bucket capacity; P(deg>96)~1e-15 for uniform 320k/10k

typedef __attribute__((ext_vector_type(8))) short sh8;
typedef __attribute__((ext_vector_type(4))) float f32x4;

__device__ __forceinline__ ushort f2b(float f) {
    uint u = __builtin_bit_cast(uint, f);
    u = (u + 0x7FFFu + ((u >> 16) & 1u)) >> 16;
    return (ushort)u;
}
__device__ __forceinline__ float b2f(ushort h) {
    uint u = ((uint)h) << 16;
    return __builtin_bit_cast(float, u);
}

// fused prep: [0,2500) x->bf16 (4/thread); [2500,3012) W1t; [3012,3524) W2t;
// [3524,3564) zero cursor
__global__ void k_conv(const float* __restrict__ x, ushort* __restrict__ xb,
                       const float* __restrict__ W1, ushort* __restrict__ W1t,
                       const float* __restrict__ W2, ushort* __restrict__ W2t,
                       int* __restrict__ cursor) {
    const int b = blockIdx.x, t = threadIdx.x;
    if (b < 2500) {
        size_t i = ((size_t)b * 256 + t) * 4;
        float4 f = *(const float4*)&x[i];
        *(ushort4*)&xb[i] = make_ushort4(f2b(f.x), f2b(f.y), f2b(f.z), f2b(f.w));
    } else if (b < 3012) {
        int idx = (b - 2500) * 256 + t;          // n*256 + k
        int n = idx >> 8, k = idx & 255;
        W1t[idx] = f2b(W1[(size_t)k * HID_DIM + n]);
    } else if (b < 3524) {
        int idx = (b - 3012) * 256 + t;          // n*512 + k
        int n = idx >> 9, k = idx & 511;
        W2t[idx] = f2b(W2[(size_t)k * OUT_DIM + n]);
    } else {
        int idx = (b - 3524) * 256 + t;
        cursor[idx] = 0;                          // 40*256 = 10240 exactly
    }
}

// bucket fill, src index only; cursor ends up holding in-degree
__global__ void k_fill(const int* __restrict__ src, const int* __restrict__ dst,
                       int* cursor, int* __restrict__ edges, int e) {
    int i = blockIdx.x * blockDim.x + threadIdx.x;
    if (i < e) {
        int d = dst[i];
        int pos = atomicAdd(&cursor[d], 1);
        if (pos < CAP) edges[(size_t)d * CAP + pos] = src[i];
    }
}

// Pull aggregation over bf16 [NN][256] table (round-6 form — best known).
// One wave per node; half-wave owns a contiguous edge sub-range, 16B (8 dims)/lane;
// unroll x4 -> 8 independent row gathers in flight per wave.
// dinv computed on the fly: rsqrt(1 + cnt[·]).
template <bool FINAL>
__global__ __launch_bounds__(256) void k_agg(const ushort* __restrict__ tbl,
                                             const int* __restrict__ cnt,
                                             const int* __restrict__ edges,
                                             const float* __restrict__ bias,
                                             const float* __restrict__ pert,
                                             void* __restrict__ outv) {
    const int t = threadIdx.x;
    const int v = blockIdx.x * 4 + (t >> 6);
    const int lane = t & 63;
    const int half = lane >> 5;
    const int d0 = (lane & 31) * 8;          // 8 dims (16B) per lane
    const int deg = min(cnt[v], CAP);
    const float dv = rsqrtf((float)(deg + 1));
    const int m0 = (deg + 1) >> 1;           // half 0: m0 edges, half 1: deg-m0
    const int* ep = edges + (size_t)v * CAP + (half ? m0 : 0);
    const int n = half ? (deg - m0) : m0;

    float a[8];
    if (half == 0) {
        sh8 hv = *(const sh8*)&tbl[(size_t)v * 256 + d0];
#pragma unroll
        for (int j = 0; j < 8; ++j) a[j] = b2f((ushort)hv[j]) * dv;
    } else {
#pragma unroll
        for (int j = 0; j < 8; ++j) a[j] = 0.f;
    }

    int i = 0;
    for (; i + 4 <= n; i += 4) {
        int s0 = ep[i], s1 = ep[i + 1], s2 = ep[i + 2], s3 = ep[i + 3];
        float w0 = rsqrtf((float)(cnt[s0] + 1));
        float w1 = rsqrtf((float)(cnt[s1] + 1));
        float w2 = rsqrtf((float)(cnt[s2] + 1));
        float w3 = rsqrtf((float)(cnt[s3] + 1));
        sh8 r0 = *(const sh8*)&tbl[(size_t)s0 * 256 + d0];
        sh8 r1 = *(const sh8*)&tbl[(size_t)s1 * 256 + d0];
        sh8 r2 = *(const sh8*)&tbl[(size_t)s2 * 256 + d0];
        sh8 r3 = *(const sh8*)&tbl[(size_t)s3 * 256 + d0];
#pragma unroll
        for (int j = 0; j < 8; ++j) a[j] = fmaf(b2f((ushort)r0[j]), w0, a[j]);
#pragma unroll
        for (int j = 0; j < 8; ++j) a[j] = fmaf(b2f((ushort)r1[j]), w1, a[j]);
#pragma unroll
        for (int j = 0; j < 8; ++j) a[j] = fmaf(b2f((ushort)r2[j]), w2, a[j]);
#pragma unroll
        for (int j = 0; j < 8; ++j) a[j] = fmaf(b2f((ushort)r3[j]), w3, a[j]);
    }
    for (; i < n; ++i) {
        int s0 = ep[i];
        float w0 = rsqrtf((float)(cnt[s0] + 1));
        sh8 r0 = *(const sh8*)&tbl[(size_t)s0 * 256 + d0];
#pragma unroll
        for (int j = 0; j < 8; ++j) a[j] = fmaf(b2f((ushort)r0[j]), w0, a[j]);
    }

    // combine halves (lanes l, l^32 own the same dims)
#pragma unroll
    for (int j = 0; j < 8; ++j) a[j] = (a[j] + __shfl_xor(a[j], 32)) * dv;

    // half 0 writes dims d0..d0+3, half 1 writes d0+4..d0+7
    const int jb = half * 4;
    const size_t o = (size_t)v * 256 + d0 + jb;
    if (FINAL) {
        float* out = (float*)outv;
        float4 pv = *(const float4*)&pert[o];
        float4 bv = *(const float4*)&bias[d0 + jb];
        *(float4*)&out[o] = make_float4(a[jb + 0] + bv.x + pv.x, a[jb + 1] + bv.y + pv.y,
                                        a[jb + 2] + bv.z + pv.z, a[jb + 3] + bv.w + pv.w);
    } else {
        ushort* out = (ushort*)outv;
        *(ushort4*)&out[o] = make_ushort4(f2b(a[jb + 0]), f2b(a[jb + 1]),
                                          f2b(a[jb + 2]), f2b(a[jb + 3]));
    }
}

// bf16 MFMA GEMM: C[M,N] = A[M,K] @ Bt[N,K]^T. Tile 128(M)x64(N), BK=64,
// 4 waves each owning 32x64 (2x4 frags), 16 MFMA / 12 ds_read_b128 per K-tile.
// 1-D grid, bn-fastest, bijective XCD swizzle (m204): consecutive tids share an
// A-panel and land on ONE XCD L2 (round-5's tile failed only for lack of this).
// OOB A-tile rows read adjacent workspace (valid memory, discarded by epilogue).
template <bool BIAS>
__global__ __launch_bounds__(256) void k_gemm(const ushort* __restrict__ A,
                                              const ushort* __restrict__ Bt,
                                              const float* __restrict__ bias,
                                              const float* __restrict__ pert,
                                              ushort* __restrict__ C,
                                              int M, int N, int K) {
    __shared__ ushort As[128][72];  // stride 144B: frag-read aliasing 2-way (free)
    __shared__ ushort Bs[64][72];
    // XCD swizzle: hw id -> logical tile id (bijective for any T)
    const int T = gridDim.x;
    const int q = T >> 3, r = T & 7;
    const int xcd = blockIdx.x & 7, j = blockIdx.x >> 3;
    const int tid = (xcd < r ? xcd * (q + 1) : r * (q + 1) + (xcd - r) * q) + j;
    const int nbx = N >> 6;
    const int bm = (tid / nbx) * 128;
    const int bn = (tid % nbx) * 64;

    const int t = threadIdx.x;
    const int lane = t & 63;
    const int w = t >> 6;
    const int wm = w * 32;
    const int fr = lane & 15, kb = (lane >> 4) * 8;
    const int rs = t >> 3, cs = (t & 7) * 8;   // staging: row 0..31, k-chunk

    f32x4 acc[2][4] = {};

    for (int k0 = 0; k0 < K; k0 += 64) {
        uint4 av[4], bv[2];
#pragma unroll
        for (int p = 0; p < 4; ++p)
            av[p] = *(const uint4*)&A[(size_t)(bm + rs + p * 32) * K + k0 + cs];
#pragma unroll
        for (int p = 0; p < 2; ++p)
            bv[p] = *(const uint4*)&Bt[(size_t)(bn + rs + p * 32) * K + k0 + cs];
        __syncthreads();
#pragma unroll
        for (int p = 0; p < 4; ++p) *(uint4*)&As[rs + p * 32][cs] = av[p];
#pragma unroll
        for (int p = 0; p < 2; ++p) *(uint4*)&Bs[rs + p * 32][cs] = bv[p];
        __syncthreads();
#pragma unroll
        for (int ks = 0; ks < 2; ++ks) {
            const int ko = ks * 32 + kb;
            sh8 af[2], bf[4];
#pragma unroll
            for (int fi = 0; fi < 2; ++fi) af[fi] = *(const sh8*)&As[wm + fi * 16 + fr][ko];
#pragma unroll
            for (int fn = 0; fn < 4; ++fn) bf[fn] = *(const sh8*)&Bs[fn * 16 + fr][ko];
#pragma unroll
            for (int fi = 0; fi < 2; ++fi)
#pragma unroll
                for (int fn = 0; fn < 4; ++fn)
                    acc[fi][fn] = __builtin_amdgcn_mfma_f32_16x16x32_bf16(
                        af[fi], bf[fn], acc[fi][fn], 0, 0, 0);
        }
    }

    // epilogue: row invariant in inner loop -> contiguous stores per (fi,i)
#pragma unroll
    for (int fi = 0; fi < 2; ++fi)
#pragma unroll
        for (int i = 0; i < 4; ++i) {
            int row = bm + wm + fi * 16 + (lane >> 4) * 4 + i;
            if (row < M) {
#pragma unroll
                for (int fn = 0; fn < 4; ++fn) {
                    int col = bn + fn * 16 + fr;
                    float val = acc[fi][fn][i];
                    if (BIAS) val += bias[col] + pert[(size_t)row * N + col];
                    C[(size_t)row * N + col] = f2b(val);
                }
            }
        }
}

extern "C" void kernel_launch(void* const* d_in, const int* in_sizes, int n_in,
                              void* d_out, int out_size, void* d_ws, size_t ws_size,
                              hipStream_t stream) {
    const float* x  = (const float*)d_in[0];
    const int*   ei = (const int*)d_in[1];
    const float* pf = (const float*)d_in[2];
    const float* pl = (const float*)d_in[3];
    const float* W1 = (const float*)d_in[4];
    const float* b1 = (const float*)d_in[5];
    const float* W2 = (const float*)d_in[6];
    const float* b2 = (const float*)d_in[7];
    float* out = (float*)d_out;

    const int* src = ei;
    const int* dst = ei + NE;

    // workspace layout (bytes, all 16B-aligned)
    char* p = (char*)d_ws;
    int*    cursor = (int*)p;            p += 10240 * 4;     // degree counts after fill
    int*    edges  = (int*)p;            p += (size_t)NN * CAP * 4;      // 3.84 MB
    ushort* xb     = (ushort*)p;         p += (size_t)NN * IN_DIM * 2;   // bf16 x
    ushort* xa     = (ushort*)p;         p += (size_t)NN * IN_DIM * 2;   // agg(x)
    ushort* W1t    = (ushort*)p;         p += (size_t)IN_DIM * HID_DIM * 2;
    ushort* W2t    = (ushort*)p;         p += (size_t)HID_DIM * OUT_DIM * 2;
    ushort* hmid   = (ushort*)p;         p += (size_t)NN * HID_DIM * 2;  // agg(x)@W1+b1+pf
    ushort* h2     = (ushort*)p;         p += (size_t)NN * OUT_DIM * 2;  // hmid@W2

    // fused prep (xb, W1t, W2t, zero cursor) then bucket fill (cursor -> degrees)
    k_conv<<<3564, 256, 0, stream>>>(x, xb, W1, W1t, W2, W2t, cursor);
    k_fill<<<(NE + 255) / 256, 256, 0, stream>>>(src, dst, cursor, edges, NE);

    const int nby = (NN + 127) / 128;   // 79

    // layer 1: agg first (256 dims), then GEMM (+b1+perturb_first) -> hmid bf16
    k_agg<false><<<NN / 4, 256, 0, stream>>>(xb, cursor, edges, nullptr, nullptr, xa);
    k_gemm<true><<<(HID_DIM / 64) * nby, 256, 0, stream>>>(
        xa, W1t, b1, pf, hmid, NN, HID_DIM, IN_DIM);

    // layer 2: GEMM first -> h2 bf16 (256 dims), then agg (+b2+perturb_last) -> out f32
    k_gemm<false><<<(OUT_DIM / 64) * nby, 256, 0, stream>>>(
        hmid, W2t, nullptr, nullptr, h2, NN, OUT_DIM, HID_DIM);
    k_agg<true><<<NN / 4, 256, 0, stream>>>(h2, cursor, edges, b2, pl, (void*)out);
}

// Round 9
// 88.624 us; speedup vs baseline: 1.4746x; 1.4746x over previous
//
#include <hip/hip_runtime.h>
#include <hip/hip_bf16.h>

#define NN 10000
#define NE 320000
#define IN_DIM 256
#define HID_DIM 512
#define OUT_DIM 256
#define CAP 96   // per-node edge bucket capacity; P(deg>96)~1e-15 for uniform 320k/10k

typedef __attribute__((ext_vector_type(8))) short sh8;
typedef __attribute__((ext_vector_type(4))) float f32x4;

__device__ __forceinline__ ushort f2b(float f) {
    uint u = __builtin_bit_cast(uint, f);
    u = (u + 0x7FFFu + ((u >> 16) & 1u)) >> 16;
    return (ushort)u;
}
__device__ __forceinline__ float b2f(ushort h) {
    uint u = ((uint)h) << 16;
    return __builtin_bit_cast(float, u);
}

// async global->LDS, 16B per lane. LDS dest = wave-uniform base + lane*16 (HW rule).
__device__ __forceinline__ void g2l16(const ushort* g, ushort* l) {
    __builtin_amdgcn_global_load_lds(
        (const __attribute__((address_space(1))) void*)g,
        (__attribute__((address_space(3))) void*)l,
        16, 0, 0);
}

// fused prep: [0,2500) x->bf16 (4/thread); [2500,3012) W1t; [3012,3524) W2t;
// [3524,3564) zero cursor
__global__ void k_conv(const float* __restrict__ x, ushort* __restrict__ xb,
                       const float* __restrict__ W1, ushort* __restrict__ W1t,
                       const float* __restrict__ W2, ushort* __restrict__ W2t,
                       int* __restrict__ cursor) {
    const int b = blockIdx.x, t = threadIdx.x;
    if (b < 2500) {
        size_t i = ((size_t)b * 256 + t) * 4;
        float4 f = *(const float4*)&x[i];
        *(ushort4*)&xb[i] = make_ushort4(f2b(f.x), f2b(f.y), f2b(f.z), f2b(f.w));
    } else if (b < 3012) {
        int idx = (b - 2500) * 256 + t;          // n*256 + k
        int n = idx >> 8, k = idx & 255;
        W1t[idx] = f2b(W1[(size_t)k * HID_DIM + n]);
    } else if (b < 3524) {
        int idx = (b - 3012) * 256 + t;          // n*512 + k
        int n = idx >> 9, k = idx & 511;
        W2t[idx] = f2b(W2[(size_t)k * OUT_DIM + n]);
    } else {
        int idx = (b - 3524) * 256 + t;
        cursor[idx] = 0;                          // 40*256 = 10240 exactly
    }
}

// bucket fill, src index only; cursor ends up holding in-degree
__global__ void k_fill(const int* __restrict__ src, const int* __restrict__ dst,
                       int* cursor, int* __restrict__ edges, int e) {
    int i = blockIdx.x * blockDim.x + threadIdx.x;
    if (i < e) {
        int d = dst[i];
        int pos = atomicAdd(&cursor[d], 1);
        if (pos < CAP) edges[(size_t)d * CAP + pos] = src[i];
    }
}

// Pull aggregation over bf16 [NN][256] table (round-6 form — best known).
// One wave per node; half-wave owns a contiguous edge sub-range, 16B (8 dims)/lane;
// unroll x4 -> 8 independent row gathers in flight per wave.
// dinv computed on the fly: rsqrt(1 + cnt[·]).
template <bool FINAL>
__global__ __launch_bounds__(256) void k_agg(const ushort* __restrict__ tbl,
                                             const int* __restrict__ cnt,
                                             const int* __restrict__ edges,
                                             const float* __restrict__ bias,
                                             const float* __restrict__ pert,
                                             void* __restrict__ outv) {
    const int t = threadIdx.x;
    const int v = blockIdx.x * 4 + (t >> 6);
    const int lane = t & 63;
    const int half = lane >> 5;
    const int d0 = (lane & 31) * 8;          // 8 dims (16B) per lane
    const int deg = min(cnt[v], CAP);
    const float dv = rsqrtf((float)(deg + 1));
    const int m0 = (deg + 1) >> 1;           // half 0: m0 edges, half 1: deg-m0
    const int* ep = edges + (size_t)v * CAP + (half ? m0 : 0);
    const int n = half ? (deg - m0) : m0;

    float a[8];
    if (half == 0) {
        sh8 hv = *(const sh8*)&tbl[(size_t)v * 256 + d0];
#pragma unroll
        for (int j = 0; j < 8; ++j) a[j] = b2f((ushort)hv[j]) * dv;
    } else {
#pragma unroll
        for (int j = 0; j < 8; ++j) a[j] = 0.f;
    }

    int i = 0;
    for (; i + 4 <= n; i += 4) {
        int s0 = ep[i], s1 = ep[i + 1], s2 = ep[i + 2], s3 = ep[i + 3];
        float w0 = rsqrtf((float)(cnt[s0] + 1));
        float w1 = rsqrtf((float)(cnt[s1] + 1));
        float w2 = rsqrtf((float)(cnt[s2] + 1));
        float w3 = rsqrtf((float)(cnt[s3] + 1));
        sh8 r0 = *(const sh8*)&tbl[(size_t)s0 * 256 + d0];
        sh8 r1 = *(const sh8*)&tbl[(size_t)s1 * 256 + d0];
        sh8 r2 = *(const sh8*)&tbl[(size_t)s2 * 256 + d0];
        sh8 r3 = *(const sh8*)&tbl[(size_t)s3 * 256 + d0];
#pragma unroll
        for (int j = 0; j < 8; ++j) a[j] = fmaf(b2f((ushort)r0[j]), w0, a[j]);
#pragma unroll
        for (int j = 0; j < 8; ++j) a[j] = fmaf(b2f((ushort)r1[j]), w1, a[j]);
#pragma unroll
        for (int j = 0; j < 8; ++j) a[j] = fmaf(b2f((ushort)r2[j]), w2, a[j]);
#pragma unroll
        for (int j = 0; j < 8; ++j) a[j] = fmaf(b2f((ushort)r3[j]), w3, a[j]);
    }
    for (; i < n; ++i) {
        int s0 = ep[i];
        float w0 = rsqrtf((float)(cnt[s0] + 1));
        sh8 r0 = *(const sh8*)&tbl[(size_t)s0 * 256 + d0];
#pragma unroll
        for (int j = 0; j < 8; ++j) a[j] = fmaf(b2f((ushort)r0[j]), w0, a[j]);
    }

    // combine halves (lanes l, l^32 own the same dims)
#pragma unroll
    for (int j = 0; j < 8; ++j) a[j] = (a[j] + __shfl_xor(a[j], 32)) * dv;

    // half 0 writes dims d0..d0+3, half 1 writes d0+4..d0+7
    const int jb = half * 4;
    const size_t o = (size_t)v * 256 + d0 + jb;
    if (FINAL) {
        float* out = (float*)outv;
        float4 pv = *(const float4*)&pert[o];
        float4 bv = *(const float4*)&bias[d0 + jb];
        *(float4*)&out[o] = make_float4(a[jb + 0] + bv.x + pv.x, a[jb + 1] + bv.y + pv.y,
                                        a[jb + 2] + bv.z + pv.z, a[jb + 3] + bv.w + pv.w);
    } else {
        ushort* out = (ushort*)outv;
        *(ushort4*)&out[o] = make_ushort4(f2b(a[jb + 0]), f2b(a[jb + 1]),
                                          f2b(a[jb + 2]), f2b(a[jb + 3]));
    }
}

// bf16 MFMA GEMM: C[M,N] = A[M,K] @ Bt[N,K]^T, 64x64 tile, 4 waves (2x2), BK=64.
// Round-6 structure + m97-style global_load_lds staging:
//  - LDS linear [64][64] (no pad), staged via g2l16: chunk = 8 rows x 1KB/wave-issue
//  - XOR swizzle both sides (rule #21): source k-chunk (l&7)^(l>>3) pre-swizzled,
//    frag read at slot kc^(fr&7) -> 2-way bank aliasing (free)
//  - staging reads up to row bm+63 (<=10047) unguarded: adjacent ws buffers are valid
// 1-D grid, bn-fastest, bijective XCD swizzle (m204) for A-panel L2 locality.
template <bool BIAS>
__global__ __launch_bounds__(256) void k_gemm(const ushort* __restrict__ A,
                                              const ushort* __restrict__ Bt,
                                              const float* __restrict__ bias,
                                              const float* __restrict__ pert,
                                              ushort* __restrict__ C,
                                              int M, int N, int K) {
    __shared__ ushort As[64][64];
    __shared__ ushort Bs[64][64];
    // XCD swizzle: hw id -> logical tile id (bijective for any T)
    const int T = gridDim.x;
    const int q = T >> 3, r = T & 7;
    const int xcd = blockIdx.x & 7, jj = blockIdx.x >> 3;
    const int tid = (xcd < r ? xcd * (q + 1) : r * (q + 1) + (xcd - r) * q) + jj;
    const int nbx = N >> 6;
    const int bm = (tid / nbx) * 64;
    const int bn = (tid % nbx) * 64;

    const int t = threadIdx.x;
    const int lane = t & 63;
    const int w = t >> 6;
    const int wm = (w >> 1) * 32, wn = (w & 1) * 32;
    const int fr = lane & 15, kb = lane >> 4;     // kb: k 16B-chunk sub-index 0..3

    // staging: wave w stages chunks {w, w+4} of As and Bs; chunk c = rows 8c..8c+7.
    // lane l -> row 8c+(l>>3), source k-chunk (l&7)^(l>>3) (inverse swizzle).
    const int rho  = lane >> 3;                   // row within chunk
    const int scol = ((lane & 7) ^ rho) * 8;      // source k offset (ushort)
    const int c0 = w, c1 = w + 4;
    ushort* lA0 = &As[0][0] + c0 * 512;           // wave-uniform LDS bases (1KB chunks)
    ushort* lA1 = &As[0][0] + c1 * 512;
    ushort* lB0 = &Bs[0][0] + c0 * 512;
    ushort* lB1 = &Bs[0][0] + c1 * 512;
    const ushort* gA0 = A  + (size_t)(bm + c0 * 8 + rho) * K + scol;
    const ushort* gA1 = A  + (size_t)(bm + c1 * 8 + rho) * K + scol;
    const ushort* gB0 = Bt + (size_t)(bn + c0 * 8 + rho) * K + scol;
    const ushort* gB1 = Bt + (size_t)(bn + c1 * 8 + rho) * K + scol;

    f32x4 acc[2][2] = {};

    for (int k0 = 0; k0 < K; k0 += 64) {
        __syncthreads();                 // prior compute done before overwrite
        g2l16(gA0, lA0); g2l16(gA1, lA1);
        g2l16(gB0, lB0); g2l16(gB1, lB1);
        gA0 += 64; gA1 += 64; gB0 += 64; gB1 += 64;
        __syncthreads();                 // compiler drains vmcnt(0) before barrier
#pragma unroll
        for (int ks = 0; ks < 2; ++ks) {
            const int slot = ((ks * 4 + kb) ^ (fr & 7)) * 8;   // swizzled read
            sh8 a0 = *(const sh8*)&As[wm + fr][slot];
            sh8 a1 = *(const sh8*)&As[wm + 16 + fr][slot];
            sh8 b0 = *(const sh8*)&Bs[wn + fr][slot];
            sh8 b1 = *(const sh8*)&Bs[wn + 16 + fr][slot];
            acc[0][0] = __builtin_amdgcn_mfma_f32_16x16x32_bf16(a0, b0, acc[0][0], 0, 0, 0);
            acc[0][1] = __builtin_amdgcn_mfma_f32_16x16x32_bf16(a0, b1, acc[0][1], 0, 0, 0);
            acc[1][0] = __builtin_amdgcn_mfma_f32_16x16x32_bf16(a1, b0, acc[1][0], 0, 0, 0);
            acc[1][1] = __builtin_amdgcn_mfma_f32_16x16x32_bf16(a1, b1, acc[1][1], 0, 0, 0);
        }
    }

    // epilogue: row invariant in inner loop -> contiguous stores per (fm,i)
#pragma unroll
    for (int fm = 0; fm < 2; ++fm)
#pragma unroll
        for (int i = 0; i < 4; ++i) {
            int row = bm + wm + fm * 16 + (lane >> 4) * 4 + i;
            if (row < M) {
#pragma unroll
                for (int fn = 0; fn < 2; ++fn) {
                    int col = bn + wn + fn * 16 + fr;
                    float val = acc[fm][fn][i];
                    if (BIAS) val += bias[col] + pert[(size_t)row * N + col];
                    C[(size_t)row * N + col] = f2b(val);
                }
            }
        }
}

extern "C" void kernel_launch(void* const* d_in, const int* in_sizes, int n_in,
                              void* d_out, int out_size, void* d_ws, size_t ws_size,
                              hipStream_t stream) {
    const float* x  = (const float*)d_in[0];
    const int*   ei = (const int*)d_in[1];
    const float* pf = (const float*)d_in[2];
    const float* pl = (const float*)d_in[3];
    const float* W1 = (const float*)d_in[4];
    const float* b1 = (const float*)d_in[5];
    const float* W2 = (const float*)d_in[6];
    const float* b2 = (const float*)d_in[7];
    float* out = (float*)d_out;

    const int* src = ei;
    const int* dst = ei + NE;

    // workspace layout (bytes, all 16B-aligned). Adjacency matters: gemm staging
    // reads up to 47 rows past M in A-buffers (xa->W1t, hmid->h2 both valid).
    char* p = (char*)d_ws;
    int*    cursor = (int*)p;            p += 10240 * 4;     // degree counts after fill
    int*    edges  = (int*)p;            p += (size_t)NN * CAP * 4;      // 3.84 MB
    ushort* xb     = (ushort*)p;         p += (size_t)NN * IN_DIM * 2;   // bf16 x
    ushort* xa     = (ushort*)p;         p += (size_t)NN * IN_DIM * 2;   // agg(x)
    ushort* W1t    = (ushort*)p;         p += (size_t)IN_DIM * HID_DIM * 2;
    ushort* W2t    = (ushort*)p;         p += (size_t)HID_DIM * OUT_DIM * 2;
    ushort* hmid   = (ushort*)p;         p += (size_t)NN * HID_DIM * 2;  // agg(x)@W1+b1+pf
    ushort* h2     = (ushort*)p;         p += (size_t)NN * OUT_DIM * 2;  // hmid@W2

    // fused prep (xb, W1t, W2t, zero cursor) then bucket fill (cursor -> degrees)
    k_conv<<<3564, 256, 0, stream>>>(x, xb, W1, W1t, W2, W2t, cursor);
    k_fill<<<(NE + 255) / 256, 256, 0, stream>>>(src, dst, cursor, edges, NE);

    const int nby = (NN + 63) / 64;   // 157

    // layer 1: agg first (256 dims), then GEMM (+b1+perturb_first) -> hmid bf16
    k_agg<false><<<NN / 4, 256, 0, stream>>>(xb, cursor, edges, nullptr, nullptr, xa);
    k_gemm<true><<<(HID_DIM / 64) * nby, 256, 0, stream>>>(
        xa, W1t, b1, pf, hmid, NN, HID_DIM, IN_DIM);

    // layer 2: GEMM first -> h2 bf16 (256 dims), then agg (+b2+perturb_last) -> out f32
    k_gemm<false><<<(OUT_DIM / 64) * nby, 256, 0, stream>>>(
        hmid, W2t, nullptr, nullptr, h2, NN, OUT_DIM, HID_DIM);
    k_agg<true><<<NN / 4, 256, 0, stream>>>(h2, cursor, edges, b2, pl, (void*)out);
}